// Round 2
// baseline (965.892 us; speedup 1.0000x reference)
//
#include <hip/hip_runtime.h>
#include <hip/hip_bf16.h>
#include <math.h>

typedef __attribute__((ext_vector_type(4))) float f32x4;
typedef __attribute__((ext_vector_type(8))) short bf16x8;

#define MFMA16(A,Bv,C) __builtin_amdgcn_mfma_f32_16x16x32_bf16(A,Bv,C,0,0,0)

// ---------------- ws layout (float offsets) ----------------
// partial-sum slices for split-K GEMMs, then small activation buffers
#define OF_PATTG  0          // 8 x [64,4096]
#define OF_PLANG  2097152    // 6 x [64,4096]  (slices 0-3: Wih part, 4-5: Whh part)
#define OF_PGATES 3670016    // 8 x [64,2048]
#define OF_PATTH  4718592    // 4 x [64,1536]
#define OF_P23    5111808    // 8 x [64,1024]
#define OF_HATT   5636096    // [64,1024]
#define OF_ATT1   5701632
#define OF_ATT2   5767168
#define OF_ATT3   5832704
#define OF_UV     5898240    // [64,2048]
#define OF_ATT    6029312    // [64,1024]
#define OF_IDX    6094848    // [64] int

// output offsets (floats): out | h_att | h_lang | c_att | c_lang
#define OUT_H0 65536
#define OUT_H1 131072
#define OUT_C0 196608
#define OUT_C1 262144

__device__ inline float sigf(float x){ return 1.f/(1.f+__expf(-x)); }
__device__ inline float tanhf_(float x){
  float ax = fabsf(x);
  float e = __expf(-2.f*ax);
  float r = (1.f-e)/(1.f+e);
  return copysignf(r, x);
}
__device__ inline float wred_sum(float v){
  #pragma unroll
  for (int o=32;o;o>>=1) v += __shfl_xor(v,o);
  return v;
}
__device__ inline float wred_max(float v){
  #pragma unroll
  for (int o=32;o;o>>=1) v = fmaxf(v, __shfl_xor(v,o));
  return v;
}

// split one f32x8 (as two f32x4) into bf16 hi + bf16 lo fragments (RNE)
__device__ inline void cvt_split8(const f32x4& x, const f32x4& y, bf16x8& h, bf16x8& l){
  #pragma unroll
  for (int i=0;i<4;i++){
    float f = x[i];
    __bf16 hb = (__bf16)f;
    h[i] = __builtin_bit_cast(short, hb);
    l[i] = __builtin_bit_cast(short, (__bf16)(f - (float)hb));
  }
  #pragma unroll
  for (int i=0;i<4;i++){
    float f = y[i];
    __bf16 hb = (__bf16)f;
    h[4+i] = __builtin_bit_cast(short, hb);
    l[4+i] = __builtin_bit_cast(short, (__bf16)(f - (float)hb));
  }
}

// ---------------- generic split-K GEMM: C[b,j] = sum_k A[b,k]*W[j,k] ----------------
// A: [64,K] via up-to-4 k-segments of width 1024 each (handles concatenated inputs)
// W: row j, k-segment s: ptr = wb[s][j>>jshift] + (j&mask)*wld[s] + k + wkoff[s]
// grid: (J/64 [+guard], slices). block: 256 = 4 waves; wave tile = 64b x 16j.
struct KSegA { const float* p; int stride; };
struct GemmDesc {
  KSegA a[4];
  const float* wb[4][3];
  int wld[4];
  int wkoff[4];
  int jshift;
  int J;
  int steps;     // k-steps (of 32) per slice
  float* C;      // partial base; slice s writes C + s*64*J
};

__global__ __launch_bounds__(256) void gemm_k(GemmDesc dA, GemmDesc dB, int nyA)
{
  const bool useA = (int)blockIdx.y < nyA;
  const GemmDesc& d = useA ? dA : dB;
  const int s  = useA ? (int)blockIdx.y : ((int)blockIdx.y - nyA);
  const int jb = blockIdx.x;
  if ((jb<<6) >= d.J) return;
  const int t    = threadIdx.x;
  const int lane = t & 63;
  const int wv   = t >> 6;
  const int lr   = lane & 15;
  const int kg   = lane >> 4;
  const int jj   = (jb<<6) + (wv<<4) + lr;
  const int jseg = jj >> d.jshift;
  const int jin  = jj & ((1<<d.jshift)-1);
  const int kb0  = s*d.steps*32 + kg*8;

  f32x4 acc[4] = {{0.f,0.f,0.f,0.f},{0.f,0.f,0.f,0.f},{0.f,0.f,0.f,0.f},{0.f,0.f,0.f,0.f}};
  f32x4 w0[2], a0[4][2], w1[2], a1[4][2];

  auto LOAD = [&](int st, f32x4 wr[2], f32x4 ar[4][2]){
    const int k   = kb0 + (st<<5);
    const int seg = k >> 10;
    const int kin = k & 1023;
    const float* wp = d.wb[seg][jseg] + (size_t)jin*(size_t)d.wld[seg] + (size_t)(k + d.wkoff[seg]);
    wr[0] = *(const f32x4*)wp;
    wr[1] = *(const f32x4*)(wp+4);
    const float* ab = d.a[seg].p + kin;
    const int astr = d.a[seg].stride;
    #pragma unroll
    for (int mi=0; mi<4; mi++){
      const float* ap = ab + (size_t)((mi<<4)+lr)*(size_t)astr;
      ar[mi][0] = *(const f32x4*)ap;
      ar[mi][1] = *(const f32x4*)(ap+4);
    }
  };
  auto COMP = [&](f32x4 wr[2], f32x4 ar[4][2]){
    bf16x8 wh, wlo;
    cvt_split8(wr[0], wr[1], wh, wlo);
    #pragma unroll
    for (int mi=0; mi<4; mi++){
      bf16x8 ah, alo;
      cvt_split8(ar[mi][0], ar[mi][1], ah, alo);
      acc[mi] = MFMA16(ah, wh,  acc[mi]);
      acc[mi] = MFMA16(alo, wh, acc[mi]);
      acc[mi] = MFMA16(ah, wlo, acc[mi]);
    }
  };

  LOAD(0, w0, a0);
  for (int st=0; st<d.steps; st+=2){   // steps always even
    LOAD(st+1, w1, a1);
    COMP(w0, a0);
    if (st+2 < d.steps) LOAD(st+2, w0, a0);
    COMP(w1, a1);
  }

  float* Cs = d.C + (size_t)s*((size_t)64*(size_t)d.J) + jj;
  #pragma unroll
  for (int mi=0; mi<4; mi++){
    #pragma unroll
    for (int r=0; r<4; r++){
      const int bb = (mi<<4) + (kg<<2) + r;   // D row = (lane>>4)*4 + reg
      Cs[(size_t)bb*(size_t)d.J] = acc[mi][r];
    }
  }
}

// ---------------- att-LSTM cell epilogue ----------------
__global__ __launch_bounds__(256) void ep_att_cell_k(const float* __restrict__ P,
    const float* __restrict__ bih, const float* __restrict__ bhh,
    const float* __restrict__ c0, float* __restrict__ hatt, float* __restrict__ out)
{
  const int b = blockIdx.x, t = threadIdx.x;
  const int r = t<<2;
  f32x4 g[4];
  #pragma unroll
  for (int q=0;q<4;q++){
    const int j = (q<<10) + r;
    f32x4 a = *(const f32x4*)(bih + j);
    a += *(const f32x4*)(bhh + j);
    #pragma unroll
    for (int s=0;s<8;s++) a += *(const f32x4*)(P + (size_t)s*(64*4096) + ((size_t)b<<12) + j);
    g[q] = a;
  }
  f32x4 c0v = *(const f32x4*)(c0 + ((size_t)b<<10) + r);
  f32x4 h, c;
  #pragma unroll
  for (int i=0;i<4;i++){
    float ii = sigf(g[0][i]);
    float ff = sigf(g[1][i]);
    float gg = tanhf_(g[2][i]);
    float oo = sigf(g[3][i]);
    float cc = ff*c0v[i] + ii*gg;
    c[i] = cc;
    h[i] = oo*tanhf_(cc);
  }
  *(f32x4*)(hatt + ((size_t)b<<10) + r) = h;
  *(f32x4*)(out + OUT_H0 + ((size_t)b<<10) + r) = h;
  *(f32x4*)(out + OUT_C0 + ((size_t)b<<10) + r) = c;
}

// ---------------- attention 1: scores + softmax + argmax + weighted sum ----------------
__global__ __launch_bounds__(256) void att1_k(const float* __restrict__ Patth,
    const float* __restrict__ hbias, const float* __restrict__ aW,
    const float* __restrict__ p_att, const float* __restrict__ feats,
    const float* __restrict__ mask, float* __restrict__ att1o, int* __restrict__ idxo)
{
  const int b = blockIdx.x, t = threadIdx.x;
  const int lane = t & 63, wv = t >> 6;
  const int a0 = lane << 3;

  f32x4 h0 = *(const f32x4*)(hbias + a0);
  f32x4 h1 = *(const f32x4*)(hbias + a0 + 4);
  #pragma unroll
  for (int s=0;s<4;s++){
    const float* pp = Patth + (size_t)s*(64*1536) + (size_t)b*1536 + a0;
    h0 += *(const f32x4*)pp;
    h1 += *(const f32x4*)(pp+4);
  }
  f32x4 w0v = *(const f32x4*)(aW + a0);
  f32x4 w1v = *(const f32x4*)(aW + a0 + 4);

  __shared__ float scl[40];
  __shared__ float wl[40];

  for (int n=wv; n<36; n+=4){
    const float* pr = p_att + (((size_t)b*36 + n)<<9) + a0;
    f32x4 p0 = *(const f32x4*)pr;
    f32x4 p1 = *(const f32x4*)(pr+4);
    float acc = 0.f;
    #pragma unroll
    for (int i=0;i<4;i++){
      acc += tanhf_(p0[i]+h0[i])*w0v[i];
      acc += tanhf_(p1[i]+h1[i])*w1v[i];
    }
    acc = wred_sum(acc);
    if (lane==0) scl[n] = acc;
  }
  __syncthreads();
  if (wv==0){
    float v = (lane<36) ? scl[lane] : -3.0e38f;
    float m = wred_max(v);
    float e = (lane<36) ? __expf(v-m) : 0.f;
    float s1 = wred_sum(e);
    float wgt = e/s1;
    float mk = (lane<36) ? mask[b*36+lane] : 0.f;
    wgt *= mk;
    float s2 = wred_sum(wgt);
    wgt = wgt/(s2+1e-8f);
    if (lane<36) wl[lane] = wgt;
    float wm = wred_max((lane<36)?wgt:-3.0e38f);
    unsigned long long bal = __ballot((lane<36) && (wgt==wm));
    if (lane==0) idxo[b] = __ffsll(bal)-1;
  }
  __syncthreads();
  f32x4 racc = {0.f,0.f,0.f,0.f};
  const int d0 = t<<2;
  for (int n=0;n<36;n++){
    f32x4 fv = *(const f32x4*)(feats + (((size_t)b*36+n)<<10) + d0);
    racc += wl[n]*fv;
  }
  *(f32x4*)(att1o + ((size_t)b<<10) + d0) = racc;
}

// ---------------- attentions 2&3 (gathered by idx), grid.y selects which ----------------
__global__ __launch_bounds__(256) void atts23_k(const float* __restrict__ Patth,
    const float* __restrict__ hb2, const float* __restrict__ hb3,
    const float* __restrict__ aW2, const float* __restrict__ aW3,
    const float* __restrict__ p2b, const float* __restrict__ p3b,
    const float* __restrict__ f2b, const float* __restrict__ f3b,
    const float* __restrict__ m2b, const float* __restrict__ m3b,
    const int* __restrict__ idxp, float* __restrict__ att2o, float* __restrict__ att3o)
{
  const int b = blockIdx.x, which = blockIdx.y, t = threadIdx.x;
  const int lane = t & 63, wv = t >> 6;
  const float* hb = which ? hb3 : hb2;
  const float* aW = which ? aW3 : aW2;
  const float* pb = which ? p3b : p2b;
  const float* fb = which ? f3b : f2b;
  const float* mb = which ? m3b : m2b;
  float* outp = which ? att3o : att2o;
  const int cofs = 512 + (which<<9);
  const int ix = idxp[b];
  const size_t rbase = ((size_t)b*36 + ix)*36;
  const float* prow = pb + (rbase<<9);
  const float* frow = fb + (rbase<<10);
  const float* mrow = mb + rbase;

  const int a0 = lane << 3;
  f32x4 h0 = *(const f32x4*)(hb + a0);
  f32x4 h1 = *(const f32x4*)(hb + a0 + 4);
  #pragma unroll
  for (int s=0;s<4;s++){
    const float* pp = Patth + (size_t)s*(64*1536) + (size_t)b*1536 + cofs + a0;
    h0 += *(const f32x4*)pp;
    h1 += *(const f32x4*)(pp+4);
  }
  f32x4 w0v = *(const f32x4*)(aW + a0);
  f32x4 w1v = *(const f32x4*)(aW + a0 + 4);

  __shared__ float scl[40];
  __shared__ float wl[40];

  for (int n=wv; n<36; n+=4){
    const float* pr = prow + ((size_t)n<<9) + a0;
    f32x4 p0 = *(const f32x4*)pr;
    f32x4 p1 = *(const f32x4*)(pr+4);
    float acc = 0.f;
    #pragma unroll
    for (int i=0;i<4;i++){
      acc += tanhf_(p0[i]+h0[i])*w0v[i];
      acc += tanhf_(p1[i]+h1[i])*w1v[i];
    }
    acc = wred_sum(acc);
    if (lane==0) scl[n] = acc;
  }
  __syncthreads();
  if (wv==0){
    float v = (lane<36) ? scl[lane] : -3.0e38f;
    float m = wred_max(v);
    float e = (lane<36) ? __expf(v-m) : 0.f;
    float s1 = wred_sum(e);
    float wgt = e/s1;
    float mk = (lane<36) ? mrow[lane] : 0.f;
    wgt *= mk;
    float s2 = wred_sum(wgt);
    wgt = wgt/(s2+1e-8f);
    if (lane<36) wl[lane] = wgt;
  }
  __syncthreads();
  f32x4 racc = {0.f,0.f,0.f,0.f};
  const int d0 = t<<2;
  for (int n=0;n<36;n++){
    f32x4 fv = *(const f32x4*)(frow + ((size_t)n<<10) + d0);
    racc += wl[n]*fv;
  }
  *(f32x4*)(outp + ((size_t)b<<10) + d0) = racc;
}

// ---------------- g1 + two LayerNorms -> uv [64,2048] ----------------
__global__ __launch_bounds__(256) void uv_k(const float* __restrict__ Pg,
    const float* __restrict__ g1b, const float* __restrict__ att2, const float* __restrict__ att3,
    const float* __restrict__ ln1g, const float* __restrict__ ln1b,
    const float* __restrict__ ln2g, const float* __restrict__ ln2b,
    float* __restrict__ uv)
{
  const int b = blockIdx.x, t = threadIdx.x;
  const int r = t<<2;
  f32x4 acc = *(const f32x4*)(g1b + r);
  #pragma unroll
  for (int s=0;s<8;s++)
    acc += *(const f32x4*)(Pg + (size_t)s*(64*2048) + ((size_t)b<<11) + r);
  f32x4 a2 = *(const f32x4*)(att2 + ((size_t)b<<10) + r);
  f32x4 a3 = *(const f32x4*)(att3 + ((size_t)b<<10) + r);
  f32x4 y1, y2;
  #pragma unroll
  for (int i=0;i<4;i++){
    float g1 = sigf(acc[i]);
    y1[i] = g1*a2[i];
    y2[i] = (1.f-g1)*a3[i];
  }
  float s1=0.f,q1=0.f,s2=0.f,q2=0.f;
  #pragma unroll
  for (int i=0;i<4;i++){ s1+=y1[i]; q1+=y1[i]*y1[i]; s2+=y2[i]; q2+=y2[i]*y2[i]; }
  #pragma unroll
  for (int o=32;o;o>>=1){
    s1 += __shfl_xor(s1,o); q1 += __shfl_xor(q1,o);
    s2 += __shfl_xor(s2,o); q2 += __shfl_xor(q2,o);
  }
  __shared__ float red[4][4];
  const int wv = t>>6, lane = t&63;
  if (lane==0){ red[0][wv]=s1; red[1][wv]=q1; red[2][wv]=s2; red[3][wv]=q2; }
  __syncthreads();
  s1 = red[0][0]+red[0][1]+red[0][2]+red[0][3];
  q1 = red[1][0]+red[1][1]+red[1][2]+red[1][3];
  s2 = red[2][0]+red[2][1]+red[2][2]+red[2][3];
  q2 = red[3][0]+red[3][1]+red[3][2]+red[3][3];
  const float inv = 1.f/1024.f;
  float mu1 = s1*inv, var1 = q1*inv - mu1*mu1;
  float mu2 = s2*inv, var2 = q2*inv - mu2*mu2;
  float is1 = rsqrtf(var1+1e-6f), is2 = rsqrtf(var2+1e-6f);
  f32x4 G1 = *(const f32x4*)(ln1g + r), B1 = *(const f32x4*)(ln1b + r);
  f32x4 G2 = *(const f32x4*)(ln2g + r), B2 = *(const f32x4*)(ln2b + r);
  f32x4 u, v;
  #pragma unroll
  for (int i=0;i<4;i++){
    u[i] = (y1[i]-mu1)*is1*G1[i] + B1[i];
    v[i] = (y2[i]-mu2)*is2*G2[i] + B2[i];
  }
  *(f32x4*)(uv + ((size_t)b<<11) + r) = u;
  *(f32x4*)(uv + ((size_t)b<<11) + 1024 + r) = v;
}

// ---------------- att = g2*att1 + (1-g2)*att23 ----------------
__global__ __launch_bounds__(256) void fusion_k(const float* __restrict__ Pg,
    const float* __restrict__ g2b, const float* __restrict__ P23,
    const float* __restrict__ att1, float* __restrict__ atto)
{
  const int b = blockIdx.x, t = threadIdx.x;
  const int r = t<<2;
  f32x4 a = *(const f32x4*)(g2b + r);
  #pragma unroll
  for (int s=0;s<8;s++)
    a += *(const f32x4*)(Pg + (size_t)s*(64*2048) + ((size_t)b<<11) + 1024 + r);
  f32x4 a23 = {0.f,0.f,0.f,0.f};
  #pragma unroll
  for (int s=0;s<8;s++)
    a23 += *(const f32x4*)(P23 + (size_t)s*(64*1024) + ((size_t)b<<10) + r);
  f32x4 a1 = *(const f32x4*)(att1 + ((size_t)b<<10) + r);
  f32x4 o;
  #pragma unroll
  for (int i=0;i<4;i++){
    float g2 = sigf(a[i]);
    o[i] = g2*a1[i] + (1.f-g2)*a23[i];
  }
  *(f32x4*)(atto + ((size_t)b<<10) + r) = o;
}

// ---------------- lang-LSTM cell epilogue ----------------
__global__ __launch_bounds__(256) void ep_lang_k(const float* __restrict__ P,
    const float* __restrict__ bih, const float* __restrict__ bhh,
    const float* __restrict__ c1, float* __restrict__ out)
{
  const int b = blockIdx.x, t = threadIdx.x;
  const int r = t<<2;
  f32x4 g[4];
  #pragma unroll
  for (int q=0;q<4;q++){
    const int j = (q<<10) + r;
    f32x4 a = *(const f32x4*)(bih + j);
    a += *(const f32x4*)(bhh + j);
    #pragma unroll
    for (int s=0;s<6;s++) a += *(const f32x4*)(P + (size_t)s*(64*4096) + ((size_t)b<<12) + j);
    g[q] = a;
  }
  f32x4 c1v = *(const f32x4*)(c1 + ((size_t)b<<10) + r);
  f32x4 h, c;
  #pragma unroll
  for (int i=0;i<4;i++){
    float ii = sigf(g[0][i]);
    float ff = sigf(g[1][i]);
    float gg = tanhf_(g[2][i]);
    float oo = sigf(g[3][i]);
    float cc = ff*c1v[i] + ii*gg;
    c[i] = cc;
    h[i] = oo*tanhf_(cc);
  }
  *(f32x4*)(out + ((size_t)b<<10) + r) = h;              // output = h_lang
  *(f32x4*)(out + OUT_H1 + ((size_t)b<<10) + r) = h;     // h_state[1]
  *(f32x4*)(out + OUT_C1 + ((size_t)b<<10) + r) = c;     // c_state[1]
}

// ---------------- host launch ----------------
static void setW(GemmDesc& g, int seg, const float* p, int ld, int koff){
  for (int j=0;j<3;j++) g.wb[seg][j] = p;
  g.wld[seg]=ld; g.wkoff[seg]=koff;
}

extern "C" void kernel_launch(void* const* d_in, const int* in_sizes, int n_in,
                              void* d_out, int out_size, void* d_ws, size_t ws_size,
                              hipStream_t stream)
{
  const float* xt    = (const float*)d_in[0];
  const float* fc    = (const float*)d_in[1];
  const float* att_feats = (const float*)d_in[2];
  const float* p_att = (const float*)d_in[3];
  const float* hs    = (const float*)d_in[4];
  const float* cs    = (const float*)d_in[5];
  const float* amask = (const float*)d_in[6];
  const float* prf   = (const float*)d_in[7];
  const float* pprf  = (const float*)d_in[8];
  const float* pmask = (const float*)d_in[9];
  const float* srf   = (const float*)d_in[10];
  const float* psrf  = (const float*)d_in[11];
  const float* smask = (const float*)d_in[12];
  const float* aWih  = (const float*)d_in[13];
  const float* aWhh  = (const float*)d_in[14];
  const float* abih  = (const float*)d_in[15];
  const float* abhh  = (const float*)d_in[16];
  const float* lWih  = (const float*)d_in[17];
  const float* lWhh  = (const float*)d_in[18];
  const float* lbih  = (const float*)d_in[19];
  const float* lbhh  = (const float*)d_in[20];
  const float* W1    = (const float*)d_in[21];
  const float* b1    = (const float*)d_in[22];
  const float* aW1   = (const float*)d_in[23];
  const float* W2    = (const float*)d_in[25];
  const float* b2    = (const float*)d_in[26];
  const float* aW2   = (const float*)d_in[27];
  const float* W3    = (const float*)d_in[29];
  const float* b3    = (const float*)d_in[30];
  const float* aW3   = (const float*)d_in[31];
  const float* ln1g  = (const float*)d_in[33];
  const float* ln1b  = (const float*)d_in[34];
  const float* ln2g  = (const float*)d_in[35];
  const float* ln2b  = (const float*)d_in[36];
  const float* W23   = (const float*)d_in[37];
  const float* g1W   = (const float*)d_in[38];
  const float* g1b   = (const float*)d_in[39];
  const float* g2W   = (const float*)d_in[40];
  const float* g2b   = (const float*)d_in[41];

  float* out = (float*)d_out;
  float* wsf = (float*)d_ws;
  float* Pattg  = wsf + OF_PATTG;
  float* Plang  = wsf + OF_PLANG;
  float* Pgates = wsf + OF_PGATES;
  float* Patth  = wsf + OF_PATTH;
  float* P23    = wsf + OF_P23;
  float* hatt   = wsf + OF_HATT;
  int*   idxp   = (int*)(wsf + OF_IDX);

  // L1: att-LSTM gates GEMM (K = [prev_h|fc|xt|h0] = 4096) + lang Whh part (K=1024)
  GemmDesc attg{};
  attg.a[0] = {hs + 65536, 1024};  // prev_h = h_state[1]
  attg.a[1] = {fc, 1024};
  attg.a[2] = {xt, 1024};
  attg.a[3] = {hs, 1024};          // h0 = h_state[0]
  setW(attg,0,aWih,3072,0); setW(attg,1,aWih,3072,0); setW(attg,2,aWih,3072,0);
  setW(attg,3,aWhh,1024,-3072);
  attg.jshift=30; attg.J=4096; attg.steps=16; attg.C=Pattg;   // 8 slices

  GemmDesc lwhh{};
  lwhh.a[0] = {hs + 65536, 1024};  // h_state[1] for lang Whh
  setW(lwhh,0,lWhh,1024,0); setW(lwhh,1,lWhh,1024,0); setW(lwhh,2,lWhh,1024,0); setW(lwhh,3,lWhh,1024,0);
  lwhh.jshift=30; lwhh.J=4096; lwhh.steps=16; lwhh.C = Plang + (size_t)4*64*4096;  // slices 4,5
  gemm_k<<<dim3(64,10), 256, 0, stream>>>(attg, lwhh, 8);

  // L2: att-LSTM cell
  ep_att_cell_k<<<64,256,0,stream>>>(Pattg, abih, abhh, cs, hatt, out);

  // L3: gates GEMM (J=2048: [g1|g2], K=[xt|h_att]=2048) + h2att GEMM (J=1536: [W1|W2|W3], K=1024)
  GemmDesc gts{};
  gts.a[0]={xt,1024}; gts.a[1]={hatt,1024};
  for (int s=0;s<4;s++){ gts.wb[s][0]=g1W; gts.wb[s][1]=g2W; gts.wb[s][2]=g2W; gts.wld[s]=2048; gts.wkoff[s]=0; }
  gts.jshift=10; gts.J=2048; gts.steps=8; gts.C=Pgates;        // 8 slices

  GemmDesc ath{};
  ath.a[0]={hatt,1024};
  for (int s=0;s<4;s++){ ath.wb[s][0]=W1; ath.wb[s][1]=W2; ath.wb[s][2]=W3; ath.wld[s]=1024; ath.wkoff[s]=0; }
  ath.jshift=9; ath.J=1536; ath.steps=8; ath.C=Patth;          // 4 slices
  gemm_k<<<dim3(32,12), 256, 0, stream>>>(gts, ath, 8);

  // L4: attention 1 (score+softmax+argmax+res)
  att1_k<<<64,256,0,stream>>>(Patth, b1, aW1, p_att, att_feats, amask, wsf+OF_ATT1, idxp);

  // L5: attentions 2,3 (gathered)
  atts23_k<<<dim3(64,2),256,0,stream>>>(Patth, b2, b3, aW2, aW3,
      pprf, psrf, prf, srf, pmask, smask, idxp, wsf+OF_ATT2, wsf+OF_ATT3);

  // L6: g1 + LN1/LN2 -> uv
  uv_k<<<64,256,0,stream>>>(Pgates, g1b, wsf+OF_ATT2, wsf+OF_ATT3, ln1g, ln1b, ln2g, ln2b, wsf+OF_UV);

  // L7: att23 GEMM (J=1024, K=2048)
  GemmDesc a23{};
  a23.a[0]={wsf+OF_UV,2048}; a23.a[1]={wsf+OF_UV+1024,2048};
  for (int s=0;s<4;s++){ a23.wb[s][0]=W23; a23.wb[s][1]=W23; a23.wb[s][2]=W23; a23.wld[s]=2048; a23.wkoff[s]=0; }
  a23.jshift=30; a23.J=1024; a23.steps=8; a23.C=P23;           // 8 slices
  gemm_k<<<dim3(16,8), 256, 0, stream>>>(a23, a23, 8);

  // L8: att = g2*att1 + (1-g2)*att23
  fusion_k<<<64,256,0,stream>>>(Pgates, g2b, P23, wsf+OF_ATT1, wsf+OF_ATT);

  // L9: lang Wih GEMM (K=[att|h_att]=2048), slices 0-3 of Plang
  GemmDesc lwih{};
  lwih.a[0]={wsf+OF_ATT,1024}; lwih.a[1]={hatt,1024};
  for (int s=0;s<4;s++){ lwih.wb[s][0]=lWih; lwih.wb[s][1]=lWih; lwih.wb[s][2]=lWih; lwih.wld[s]=2048; lwih.wkoff[s]=0; }
  lwih.jshift=30; lwih.J=4096; lwih.steps=16; lwih.C=Plang;    // 4 slices
  gemm_k<<<dim3(64,4), 256, 0, stream>>>(lwih, lwih, 4);

  // L10: lang-LSTM cell -> output, h_state[1], c_state[1]
  ep_lang_k<<<64,256,0,stream>>>(Plang, lbih, lbhh, cs + 65536, out);
}